// Round 6
// baseline (225.674 us; speedup 1.0000x reference)
//
#include <hip/hip_runtime.h>

#define N_ROWS 16384
#define NCB    16
#define CB     1024
#define TPB    256
#define RPT    2            // rows per thread
#define RPB    (TPB * RPT)  // 512 rows per block

// Zeros the 4 scalar tail outputs (rate_uem accumulator + 3 literal zeros).
__global__ void zero_tail_kernel(float* p) {
    int t = threadIdx.x;
    if (t < 4) p[t] = 0.0f;
}

// Per group a: softmax over logits -> interleaved table
//   tb[a*CB + c] = { w.x, w.y, w.z, w.w } , { g, l2u, 0, 0 }
// with g = -0.5 * (||w||^2 + (-log2 pmf)/lambda), l2u = -log2 pmf.
// argmin dist == argmax( dot(x,w) + g ).
__global__ __launch_bounds__(256) void prep_kernel(
    const float4* __restrict__ cbook,
    const float*  __restrict__ logits,
    const float*  __restrict__ lmbda_p,
    float4* __restrict__ tb)            // (NCB*CB*2) float4
{
    const int a = blockIdx.x;
    const int t = threadIdx.x;
    __shared__ float sredA[4], sredB[4];

    float l[4];
    float m = -INFINITY;
#pragma unroll
    for (int r = 0; r < 4; ++r) {
        l[r] = logits[a * CB + t + 256 * r];
        m = fmaxf(m, l[r]);
    }
#pragma unroll
    for (int off = 32; off >= 1; off >>= 1) m = fmaxf(m, __shfl_down(m, off, 64));
    if ((t & 63) == 0) sredA[t >> 6] = m;
    __syncthreads();
    const float gmax = fmaxf(fmaxf(sredA[0], sredA[1]), fmaxf(sredA[2], sredA[3]));

    float s = 0.f;
#pragma unroll
    for (int r = 0; r < 4; ++r) s += __expf(l[r] - gmax);
#pragma unroll
    for (int off = 32; off >= 1; off >>= 1) s += __shfl_down(s, off, 64);
    if ((t & 63) == 0) sredB[t >> 6] = s;
    __syncthreads();
    const float lse   = gmax + __logf(sredB[0] + sredB[1] + sredB[2] + sredB[3]);
    const float inv_l = 1.0f / lmbda_p[0];
    const float INV_LN2 = 1.4426950408889634f;
#pragma unroll
    for (int r = 0; r < 4; ++r) {
        int i = t + 256 * r;
        float4 w = cbook[a * CB + i];
        float v  = (lse - l[r]) * INV_LN2;            // -log2 pmf  (>= 0)
        float cc = w.x * w.x + w.y * w.y + w.z * w.z + w.w * w.w;
        float g  = -0.5f * (cc + v * inv_l);
        tb[(size_t)(a * CB + i) * 2]     = w;
        tb[(size_t)(a * CB + i) * 2 + 1] = make_float4(g, v, 0.f, 0.f);
    }
}

// Scan: grid (16 groups, 32 row-chunks) = 512 blocks, 256 threads, 2 rows/thr.
// Codeword table addresses are block-uniform -> scalar loads; hot loop has
// zero LDS and zero per-lane VMEM.
__global__ __launch_bounds__(TPB) void scan_kernel(
    const float4* __restrict__ x,       // (N*NCB) float4 rows
    const float4* __restrict__ tb,      // interleaved table
    float4* __restrict__ xhat,          // (N*NCB) float4
    float*  __restrict__ tail)
{
    const int a     = blockIdx.x;
    const int chunk = blockIdx.y;
    const int tx    = threadIdx.x;

    const int n0 = chunk * RPB + tx;
    const int n1 = n0 + TPB;
    const float4 x0 = x[n0 * NCB + a];
    const float4 x1 = x[n1 * NCB + a];

    const float4* __restrict__ t = tb + (size_t)a * CB * 2;   // uniform

    float s0 = -INFINITY, s1 = -INFINITY;
    int   i0 = 0,         i1 = 0;
#pragma unroll 8
    for (int c = 0; c < CB; ++c) {
        const float4 w = t[2 * c];          // scalar loads (wave-uniform)
        const float  g = t[2 * c + 1].x;
        // score = dot(x, w) + g  (g seeds the fma chain; one v_mov of g
        // per codeword is shared by both rows)
        float d0 = fmaf(x0.w, w.w, g);
        d0 = fmaf(x0.z, w.z, d0);
        d0 = fmaf(x0.y, w.y, d0);
        d0 = fmaf(x0.x, w.x, d0);
        float d1 = fmaf(x1.w, w.w, g);
        d1 = fmaf(x1.z, w.z, d1);
        d1 = fmaf(x1.y, w.y, d1);
        d1 = fmaf(x1.x, w.x, d1);
        // strict '>' replace: first (lowest) index wins ties == argmin
        i0 = (d0 > s0) ? c : i0;
        s0 = fmaxf(s0, d0);
        i1 = (d1 > s1) ? c : i1;
        s1 = fmaxf(s1, d1);
    }

    // epilogue: gather winners (per-lane VMEM, 32KB table -> L1/L2)
    xhat[n0 * NCB + a] = t[2 * i0];
    xhat[n1 * NCB + a] = t[2 * i1];
    float r = t[2 * i0 + 1].y + t[2 * i1 + 1].y;

#pragma unroll
    for (int off = 32; off >= 1; off >>= 1) r += __shfl_down(r, off, 64);
    __shared__ float wsum[TPB / 64];
    if ((tx & 63) == 0) wsum[tx >> 6] = r;
    __syncthreads();
    if (tx == 0) {
        float tot = wsum[0];
#pragma unroll
        for (int w = 1; w < TPB / 64; ++w) tot += wsum[w];
        atomicAdd(&tail[0], tot);
    }
}

extern "C" void kernel_launch(void* const* d_in, const int* in_sizes, int n_in,
                              void* d_out, int out_size, void* d_ws, size_t ws_size,
                              hipStream_t stream) {
    (void)in_sizes; (void)n_in; (void)out_size; (void)ws_size;
    const float4* x      = (const float4*)d_in[0];
    const float4* cbook  = (const float4*)d_in[1];
    const float*  logits = (const float*)d_in[2];
    const float*  lmbda  = (const float*)d_in[3];

    float* out  = (float*)d_out;
    float* tail = out + (size_t)N_ROWS * NCB * 4;   // offset 1048576

    float4* tb = (float4*)d_ws;                     // 512 KB interleaved table

    zero_tail_kernel<<<1, 64, 0, stream>>>(tail);
    prep_kernel<<<NCB, 256, 0, stream>>>(cbook, logits, lmbda, tb);

    dim3 grid(NCB, N_ROWS / RPB);                   // (16, 32) = 512 blocks
    scan_kernel<<<grid, TPB, 0, stream>>>(x, tb, (float4*)d_out, tail);
}